// Round 1
// baseline (129.056 us; speedup 1.0000x reference)
//
#include <hip/hip_runtime.h>

// ChamferLoss: B=4, N=M=8192, D=3, fp32. Output = scalar.
// Fused: never materialize the [B,N,M] matrix. Pure VALU-fp32 bound (~48us floor).

#define BATCH  4
#define NPTS   8192
#define TPB    256
#define QPT    8                      // query points per thread
#define NSLICE 16                     // reference slices (parallelism)
#define NS     (NPTS / NSLICE)        // 512 ref points per block
#define QTILES (NPTS / (TPB * QPT))   // 4
#define TOTALQ (BATCH * NPTS)         // 32768 per direction

__global__ __launch_bounds__(TPB) void chamfer_init(unsigned int* minbuf, float* out) {
    int i = blockIdx.x * TPB + threadIdx.x;
    if (i < 2 * TOTALQ) minbuf[i] = 0x7F800000u;   // +inf bits
    if (i == 0) out[0] = 0.0f;
}

__global__ __launch_bounds__(TPB) void chamfer_dist(const float* __restrict__ x,
                                                    const float* __restrict__ y,
                                                    unsigned int* __restrict__ minbuf) {
    // grid: (QTILES, BATCH*NSLICE, 2)
    __shared__ float4 s4[NS];         // ref points padded to 16B -> ds_read_b128 broadcast
    const int tid   = threadIdx.x;
    const int qtile = blockIdx.x;
    const int b     = blockIdx.y / NSLICE;
    const int slice = blockIdx.y % NSLICE;
    const int dir   = blockIdx.z;

    const float* q = (dir == 0) ? x : y;
    const float* r = (dir == 0) ? y : x;
    unsigned int* mb = minbuf + dir * TOTALQ + b * NPTS;

    // stage reference slice into LDS
    const float* rbase = r + (size_t)(b * NPTS + slice * NS) * 3;
    for (int i = tid; i < NS; i += TPB) {
        float rx = rbase[i * 3 + 0];
        float ry = rbase[i * 3 + 1];
        float rz = rbase[i * 3 + 2];
        s4[i] = make_float4(rx, ry, rz, 0.0f);
    }
    __syncthreads();

    float qx[QPT], qy[QPT], qz[QPT], m[QPT];
    const int q0 = qtile * (TPB * QPT);
    #pragma unroll
    for (int k = 0; k < QPT; ++k) {
        const int qi = q0 + k * TPB + tid;
        const float* qp = q + (size_t)(b * NPTS + qi) * 3;
        qx[k] = qp[0]; qy[k] = qp[1]; qz[k] = qp[2];
        m[k] = 3.0e38f;
    }

    #pragma unroll 2
    for (int j = 0; j < NS; ++j) {
        const float4 rp = s4[j];      // wave-uniform address -> LDS broadcast
        #pragma unroll
        for (int k = 0; k < QPT; ++k) {
            float dx = qx[k] - rp.x;
            float dy = qy[k] - rp.y;
            float dz = qz[k] - rp.z;
            float d  = fmaf(dx, dx, fmaf(dy, dy, dz * dz));
            m[k] = fminf(m[k], d);
        }
    }

    // squared distances are >= 0: float bits are order-preserving as uint
    #pragma unroll
    for (int k = 0; k < QPT; ++k) {
        const int qi = q0 + k * TPB + tid;
        atomicMin(&mb[qi], __float_as_uint(m[k]));
    }
}

__global__ __launch_bounds__(TPB) void chamfer_reduce(const unsigned int* __restrict__ minbuf,
                                                      float* __restrict__ out) {
    __shared__ float ssum[TPB / 64];
    const int tid = threadIdx.x;
    float v = 0.0f;
    for (int i = blockIdx.x * TPB + tid; i < 2 * TOTALQ; i += gridDim.x * TPB)
        v += __uint_as_float(minbuf[i]);
    // wave64 reduce
    #pragma unroll
    for (int off = 32; off > 0; off >>= 1)
        v += __shfl_down(v, off, 64);
    if ((tid & 63) == 0) ssum[tid >> 6] = v;
    __syncthreads();
    if (tid == 0) {
        float w = ssum[0] + ssum[1] + ssum[2] + ssum[3];
        // mean over points (N==M==NPTS), mean over batch, x-dir + y-dir summed
        atomicAdd(out, w * (1.0f / (float)(BATCH * NPTS)));
    }
}

extern "C" void kernel_launch(void* const* d_in, const int* in_sizes, int n_in,
                              void* d_out, int out_size, void* d_ws, size_t ws_size,
                              hipStream_t stream) {
    const float* x = (const float*)d_in[0];
    const float* y = (const float*)d_in[1];
    float* out = (float*)d_out;
    unsigned int* minbuf = (unsigned int*)d_ws;   // needs 2*TOTALQ*4 = 256 KB

    chamfer_init<<<dim3((2 * TOTALQ + TPB - 1) / TPB), TPB, 0, stream>>>(minbuf, out);
    chamfer_dist<<<dim3(QTILES, BATCH * NSLICE, 2), TPB, 0, stream>>>(x, y, minbuf);
    chamfer_reduce<<<dim3(64), TPB, 0, stream>>>(minbuf, out);
}

// Round 2
// 99.109 us; speedup vs baseline: 1.3022x; 1.3022x over previous
//
#include <hip/hip_runtime.h>

// ChamferLoss: B=4, N=M=8192, D=3, fp32. Scalar out.
// Fused, VALU-bound. Inner body = 3 fma + 1 min per pair via
// d = (qn + rn) - 2 q.r  (same formula as the np reference).
// Floor: 2*4*8192*8192 pairs * 4 ops / 78.6T lane-ops/s = 27.3 us.

#define BATCH  4
#define NPTS   8192
#define TPB    256
#define QPT    8                      // query points per thread
#define NSLICE 32                     // reference slices (occupancy)
#define NS     (NPTS / NSLICE)        // 256 ref points per block
#define QTILES (NPTS / (TPB * QPT))   // 4
#define TOTALQ (BATCH * NPTS)         // 32768 per direction

__global__ __launch_bounds__(TPB) void chamfer_dist(const float* __restrict__ x,
                                                    const float* __restrict__ y,
                                                    float* __restrict__ partial,
                                                    float* __restrict__ out) {
    // grid: (QTILES, BATCH*NSLICE, 2)
    __shared__ float4 s4[NS];         // (rx, ry, rz, rn) -> one ds_read_b128 broadcast
    const int tid   = threadIdx.x;
    const int qtile = blockIdx.x;
    const int b     = blockIdx.y / NSLICE;
    const int slice = blockIdx.y % NSLICE;
    const int dir   = blockIdx.z;

    const float* q = (dir == 0) ? x : y;
    const float* r = (dir == 0) ? y : x;

    // zero the scalar output (benign identical-value race across blocks;
    // reduce kernel runs after this kernel completes -> visible & ordered)
    if (tid == 0) out[0] = 0.0f;

    // stage reference slice into LDS with precomputed ||r||^2 in .w
    const float* rbase = r + (size_t)(b * NPTS + slice * NS) * 3;
    for (int i = tid; i < NS; i += TPB) {
        float rx = rbase[i * 3 + 0];
        float ry = rbase[i * 3 + 1];
        float rz = rbase[i * 3 + 2];
        float rn = fmaf(rx, rx, fmaf(ry, ry, rz * rz));
        s4[i] = make_float4(rx, ry, rz, rn);
    }
    __syncthreads();

    float cx[QPT], cy[QPT], cz[QPT], qn[QPT], m[QPT];
    const int q0 = qtile * (TPB * QPT);
    #pragma unroll
    for (int k = 0; k < QPT; ++k) {
        const int qi = q0 + k * TPB + tid;
        const float* qp = q + (size_t)(b * NPTS + qi) * 3;
        float qx = qp[0], qy = qp[1], qz = qp[2];
        qn[k] = fmaf(qx, qx, fmaf(qy, qy, qz * qz));
        cx[k] = -2.0f * qx;
        cy[k] = -2.0f * qy;
        cz[k] = -2.0f * qz;
        m[k]  = 3.0e38f;
    }

    #pragma unroll 4
    for (int j = 0; j < NS; ++j) {
        const float4 rp = s4[j];      // wave-uniform -> LDS broadcast, no conflicts
        #pragma unroll
        for (int k = 0; k < QPT; ++k) {
            float t = fmaf(rp.x, cx[k], rp.w);   // rn - 2*qx*rx
            t = fmaf(rp.y, cy[k], t);
            t = fmaf(rp.z, cz[k], t);
            m[k] = fminf(m[k], t);
        }
    }

    // partial[(dir*BATCH + b)*NSLICE + slice][q] = min + qn (qn const per query)
    float* pb = partial + ((size_t)((dir * BATCH + b) * NSLICE + slice)) * NPTS;
    #pragma unroll
    for (int k = 0; k < QPT; ++k) {
        const int qi = q0 + k * TPB + tid;
        pb[qi] = m[k] + qn[k];
    }
}

__global__ __launch_bounds__(TPB) void chamfer_reduce(const float* __restrict__ partial,
                                                      float* __restrict__ out) {
    // grid: 2*TOTALQ/TPB = 256 blocks; one thread per (dir,b,q)
    const int tid = threadIdx.x;
    const int g   = blockIdx.x * TPB + tid;       // [0, 2*TOTALQ)
    const int db  = g / NPTS;                     // dir*BATCH + b
    const int qq  = g - db * NPTS;

    const float* p = partial + (size_t)db * NSLICE * NPTS + qq;
    float v = 3.0e38f;
    #pragma unroll
    for (int s = 0; s < NSLICE; ++s)
        v = fminf(v, p[(size_t)s * NPTS]);        // coalesced across threads

    // block sum
    float w = v;
    #pragma unroll
    for (int off = 32; off > 0; off >>= 1)
        w += __shfl_down(w, off, 64);
    __shared__ float ss[TPB / 64];
    if ((tid & 63) == 0) ss[tid >> 6] = w;
    __syncthreads();
    if (tid == 0) {
        float t = ss[0] + ss[1] + ss[2] + ss[3];
        atomicAdd(out, t * (1.0f / (float)TOTALQ));
    }
}

extern "C" void kernel_launch(void* const* d_in, const int* in_sizes, int n_in,
                              void* d_out, int out_size, void* d_ws, size_t ws_size,
                              hipStream_t stream) {
    const float* x = (const float*)d_in[0];
    const float* y = (const float*)d_in[1];
    float* out = (float*)d_out;
    float* partial = (float*)d_ws;    // 2*BATCH*NSLICE*NPTS*4 = 8 MB

    chamfer_dist<<<dim3(QTILES, BATCH * NSLICE, 2), TPB, 0, stream>>>(x, y, partial, out);
    chamfer_reduce<<<dim3((2 * TOTALQ) / TPB), TPB, 0, stream>>>(partial, out);
}

// Round 3
// 99.101 us; speedup vs baseline: 1.3023x; 1.0001x over previous
//
#include <hip/hip_runtime.h>

// ChamferLoss: B=4, N=M=8192, D=3, fp32. Scalar out.
// Fused, VALU-bound. Inner body = 3 fma + 1 min per pair via
// d = (qn + rn) - 2 q.r  (same formula as the np reference).
// Floor: 2*4*8192*8192 pairs * 4 ops / 78.6T lane-ops/s = 27.3 us.
// QPT=16 so one ds_read_b128 broadcast feeds 64 VALU wave-instrs
// (round-2's QPT=8 left the shared LDS pipe ~75% busy -> lgkm stalls).

#define BATCH  4
#define NPTS   8192
#define TPB    256
#define QPT    16                     // query points per thread
#define NSLICE 32                     // reference slices (occupancy)
#define NS     (NPTS / NSLICE)        // 256 ref points per block
#define QTILES (NPTS / (TPB * QPT))   // 2
#define TOTALQ (BATCH * NPTS)         // 32768 per direction

__global__ __launch_bounds__(TPB) void chamfer_dist(const float* __restrict__ x,
                                                    const float* __restrict__ y,
                                                    float* __restrict__ partial) {
    // grid: (QTILES, BATCH*NSLICE, 2) = 512 blocks
    __shared__ float4 s4[NS];         // (rx, ry, rz, rn) -> one ds_read_b128 broadcast
    const int tid   = threadIdx.x;
    const int qtile = blockIdx.x;
    const int b     = blockIdx.y / NSLICE;
    const int slice = blockIdx.y % NSLICE;
    const int dir   = blockIdx.z;

    const float* q = (dir == 0) ? x : y;
    const float* r = (dir == 0) ? y : x;

    // stage reference slice into LDS with precomputed ||r||^2 in .w
    const float* rbase = r + (size_t)(b * NPTS + slice * NS) * 3;
    {
        int i = tid;                  // NS == TPB: single pass
        float rx = rbase[i * 3 + 0];
        float ry = rbase[i * 3 + 1];
        float rz = rbase[i * 3 + 2];
        float rn = fmaf(rx, rx, fmaf(ry, ry, rz * rz));
        s4[i] = make_float4(rx, ry, rz, rn);
    }
    __syncthreads();

    float cx[QPT], cy[QPT], cz[QPT], qn[QPT], m[QPT];
    const int q0 = qtile * (TPB * QPT);
    #pragma unroll
    for (int k = 0; k < QPT; ++k) {
        const int qi = q0 + k * TPB + tid;
        const float* qp = q + (size_t)(b * NPTS + qi) * 3;
        float qx = qp[0], qy = qp[1], qz = qp[2];
        qn[k] = fmaf(qx, qx, fmaf(qy, qy, qz * qz));
        cx[k] = -2.0f * qx;
        cy[k] = -2.0f * qy;
        cz[k] = -2.0f * qz;
        m[k]  = 3.0e38f;
    }

    #pragma unroll 2
    for (int j = 0; j < NS; ++j) {
        const float4 rp = s4[j];      // wave-uniform -> LDS broadcast, no conflicts
        #pragma unroll
        for (int k = 0; k < QPT; ++k) {
            float t = fmaf(rp.x, cx[k], rp.w);   // rn - 2*qx*rx
            t = fmaf(rp.y, cy[k], t);
            t = fmaf(rp.z, cz[k], t);
            m[k] = fminf(m[k], t);
        }
    }

    // partial[(dir*BATCH + b)*NSLICE + slice][q] = min + qn (qn const per query)
    float* pb = partial + ((size_t)((dir * BATCH + b) * NSLICE + slice)) * NPTS;
    #pragma unroll
    for (int k = 0; k < QPT; ++k) {
        const int qi = q0 + k * TPB + tid;
        pb[qi] = m[k] + qn[k];
    }
}

__global__ __launch_bounds__(TPB) void chamfer_reduce(const float* __restrict__ partial,
                                                      float* __restrict__ out) {
    // grid: 64 blocks; each block covers one db (of 8) x 1024 q (thread = float4)
    const int tid = threadIdx.x;
    const int db    = blockIdx.x >> 3;            // [0,8): dir*BATCH + b
    const int chunk = blockIdx.x & 7;             // [0,8)
    const int f4    = chunk * TPB + tid;          // float4 index within NPTS/4

    const float4* p = (const float4*)(partial + (size_t)db * NSLICE * NPTS) + f4;
    float4 v = make_float4(3.0e38f, 3.0e38f, 3.0e38f, 3.0e38f);
    #pragma unroll
    for (int s = 0; s < NSLICE; ++s) {
        float4 t = p[(size_t)s * (NPTS / 4)];     // coalesced 16B loads, full MLP
        v.x = fminf(v.x, t.x); v.y = fminf(v.y, t.y);
        v.z = fminf(v.z, t.z); v.w = fminf(v.w, t.w);
    }

    float w = (v.x + v.y) + (v.z + v.w);
    #pragma unroll
    for (int off = 32; off > 0; off >>= 1)
        w += __shfl_down(w, off, 64);
    __shared__ float ss[TPB / 64];
    if ((tid & 63) == 0) ss[tid >> 6] = w;
    __syncthreads();
    if (tid == 0) {
        float t = ss[0] + ss[1] + ss[2] + ss[3];
        atomicAdd(out, t * (1.0f / (float)TOTALQ));
    }
}

extern "C" void kernel_launch(void* const* d_in, const int* in_sizes, int n_in,
                              void* d_out, int out_size, void* d_ws, size_t ws_size,
                              hipStream_t stream) {
    const float* x = (const float*)d_in[0];
    const float* y = (const float*)d_in[1];
    float* out = (float*)d_out;
    float* partial = (float*)d_ws;    // 2*BATCH*NSLICE*NPTS*4 = 8 MB

    hipMemsetAsync(out, 0, sizeof(float), stream);
    chamfer_dist<<<dim3(QTILES, BATCH * NSLICE, 2), TPB, 0, stream>>>(x, y, partial);
    chamfer_reduce<<<dim3(64), TPB, 0, stream>>>(partial, out);
}